// Round 9
// baseline (262.667 us; speedup 1.0000x reference)
//
#include <hip/hip_runtime.h>
#include <hip/hip_bf16.h>

#define DIM 64
#define SCALE 0.125f
#define SCAP 4608             // super-slot capacity (mean 4096, sd ~64 -> +8 sd)
#define CHUNK1 4096           // edges per k_bin1 block
#define BCAP 768              // 32-node group capacity (mean 512, sd ~22.6)

// ---------------- bf16 helpers (manual, RNE) ----------------
static __device__ __forceinline__ unsigned int pack2bf(float a, float b) {
    unsigned int ua = __float_as_uint(a), ub = __float_as_uint(b);
    ua += 0x7fffu + ((ua >> 16) & 1u);
    ub += 0x7fffu + ((ub >> 16) & 1u);
    return (ua >> 16) | (ub & 0xffff0000u);
}
static __device__ __forceinline__ float2 unpack2bf(unsigned int u) {
    return make_float2(__uint_as_float(u << 16), __uint_as_float(u & 0xffff0000u));
}

// ---------------- Wvo = Wv @ Wo ----------------
// 64 blocks x 64 threads: Wv[r][k] is wave-uniform (s_load, K$-hot),
// Wo[k][j] coalesced per-lane (L2-hot across blocks). Replaces the
// single-block LDS-serial version (~12us -> ~3us).
__global__ __launch_bounds__(64) void k_wmul(const float* __restrict__ Wv,
                                             const float* __restrict__ Wo,
                                             float* __restrict__ Wvo) {
    int r = blockIdx.x, j = threadIdx.x;
    float a = 0.f;
#pragma unroll 8
    for (int k = 0; k < 64; k++)
        a = fmaf(Wv[r * 64 + k], Wo[k * 64 + j], a);
    Wvo[r * 64 + j] = a;
}

// ---------------- pass 1: partition into 256-node super-bins ----------------
// 391 blocks (full chip vs R8's 98), LDS hist over <=400 super-bins, one
// global atomic per (block,bin) reserves a ~10.5-entry run (~42B, near
// line-clean single-CU writes; short runs at 32-node granularity were the
// cross-XCD write-amp trap).  Payload: send(17b) | local-in-super(8b)<<17.
__global__ __launch_bounds__(512) void k_bin1(const int* __restrict__ send,
                                              const int* __restrict__ recv,
                                              int* __restrict__ binCur,
                                              unsigned int* __restrict__ ebufA,
                                              int E, int NSUP) {
    __shared__ int hist[400];
    __shared__ int lcur[400];
    int tid = threadIdx.x;
    int base = blockIdx.x * CHUNK1;
    int lim = min(base + CHUNK1, E);

    for (int i = tid; i < NSUP; i += 512) hist[i] = 0;
    __syncthreads();
    for (int i = base + tid; i < lim; i += 512)
        atomicAdd(&hist[recv[i] >> 8], 1);
    __syncthreads();
    for (int i = tid; i < NSUP; i += 512) {
        int h = hist[i];
        lcur[i] = h ? atomicAdd(&binCur[i], h) : 0;
    }
    __syncthreads();
    for (int i = base + tid; i < lim; i += 512) {
        int r = recv[i];
        int b = r >> 8;
        int p = atomicAdd(&lcur[b], 1);
        if (p < SCAP)
            ebufA[(size_t)b * SCAP + p] = (unsigned)send[i] | ((unsigned)(r & 255) << 17);
    }
}

// ---------------- pass 2: sub-sort each super-slot by 32-node group ----------
// One block per super-bin: read slot coalesced, counting-sort by 3 sub-bits in
// LDS, write back fully coalesced (single-CU lines), emit sofs[] run table so
// k_attn keeps 8 blocks per super-bin (3128-block occupancy).
__global__ __launch_bounds__(256) void k_bin2(const int* __restrict__ binCur,
                                              const unsigned int* __restrict__ ebufA,
                                              unsigned int* __restrict__ ebufB,
                                              int* __restrict__ sofs) {
    __shared__ unsigned int lbuf[SCAP];
    __shared__ int scnt[8], sofs_l[9], scur[8];
    int tid = threadIdx.x;
    int j = blockIdx.x;
    int cnt = min(binCur[j], SCAP);
    const unsigned int* src = ebufA + (size_t)j * SCAP;

    if (tid < 8) scnt[tid] = 0;
    __syncthreads();
    for (int i = tid; i < cnt; i += 256)
        atomicAdd(&scnt[(src[i] >> 22) & 7], 1);
    __syncthreads();
    if (tid == 0) {
        int a = 0;
        for (int s = 0; s < 8; s++) { sofs_l[s] = a; scur[s] = a; a += scnt[s]; }
        sofs_l[8] = a;
    }
    __syncthreads();
    for (int i = tid; i < cnt; i += 256) {
        unsigned int u = src[i];
        int s = (u >> 22) & 7;
        int p = atomicAdd(&scur[s], 1);
        lbuf[p] = u;
    }
    __syncthreads();
    unsigned int* dst = ebufB + (size_t)j * SCAP;
    for (int i = tid; i < cnt; i += 256) dst[i] = lbuf[i];
    if (tid < 9) sofs[j * 9 + tid] = j * SCAP + sofs_l[tid];
}

// ---------------- QKV' GEMM, variant T: 8x8 register tiling (R8 kernel) -------
__global__ __launch_bounds__(256) void k_qkvT(const float* __restrict__ x,
                                              const float* __restrict__ Wq,
                                              const float* __restrict__ Wk,
                                              const float* __restrict__ Wvo,
                                              float* __restrict__ Q,
                                              unsigned int* __restrict__ KVb,
                                              int N, int rowBase, int nchunk) {
    __shared__ __align__(16) float ws[64 * 64];
    __shared__ __align__(16) float xs[4][64 * 64];
    int tid = threadIdx.x;
    int wv = tid >> 6;
    int lane = tid & 63;
    int m = blockIdx.x / nchunk;
    int cb = blockIdx.x % nchunk;
    const float* W = (m == 0) ? Wq : ((m == 1) ? Wk : Wvo);

    for (int i = tid; i < 1024; i += 256) ((float4*)ws)[i] = ((const float4*)W)[i];
    __syncthreads();

    int base = rowBase + cb * 256 + wv * 64;
    if (base < N) {
        float* xw = xs[wv];
#pragma unroll
        for (int c4 = 0; c4 < 16; c4++) {
            float4 v = make_float4(0.f, 0.f, 0.f, 0.f);
            if (base + lane < N) v = ((const float4*)x)[(size_t)(base + lane) * 16 + c4];
            xw[(c4 * 4 + 0) * 64 + lane] = v.x;
            xw[(c4 * 4 + 1) * 64 + lane] = v.y;
            xw[(c4 * 4 + 2) * 64 + lane] = v.z;
            xw[(c4 * 4 + 3) * 64 + lane] = v.w;
        }
        asm volatile("s_waitcnt lgkmcnt(0)" ::: "memory");

        int lr = lane >> 3;
        int lc = lane & 7;
        const float* xp = xw + lr * 8;
        const float* wp = ws + lc * 8;

        float acc[8][8];
#pragma unroll
        for (int i = 0; i < 8; i++)
#pragma unroll
            for (int j = 0; j < 8; j++) acc[i][j] = 0.f;

        float4 xa = *(const float4*)(xp);
        float4 xb = *(const float4*)(xp + 4);
        float4 wa = *(const float4*)(wp);
        float4 wb = *(const float4*)(wp + 4);
#pragma unroll 4
        for (int k = 0; k < 64; k++) {
            float4 xan, xbn, wan, wbn;
            if (k < 63) {
                xan = *(const float4*)(xp + (k + 1) * 64);
                xbn = *(const float4*)(xp + (k + 1) * 64 + 4);
                wan = *(const float4*)(wp + (k + 1) * 64);
                wbn = *(const float4*)(wp + (k + 1) * 64 + 4);
            }
            float xv[8] = {xa.x, xa.y, xa.z, xa.w, xb.x, xb.y, xb.z, xb.w};
            float wc[8] = {wa.x, wa.y, wa.z, wa.w, wb.x, wb.y, wb.z, wb.w};
#pragma unroll
            for (int i = 0; i < 8; i++)
#pragma unroll
                for (int j = 0; j < 8; j++)
                    acc[i][j] = fmaf(xv[i], wc[j], acc[i][j]);
            xa = xan; xb = xbn; wa = wan; wb = wbn;
        }

#pragma unroll
        for (int i = 0; i < 8; i++) {
            int row = base + lr * 8 + i;
            if (row < N) {
                if (m == 0) {
                    float* dst = &Q[(size_t)row * 64 + lc * 8];
                    ((float4*)dst)[0] = make_float4(acc[i][0], acc[i][1], acc[i][2], acc[i][3]);
                    ((float4*)dst)[1] = make_float4(acc[i][4], acc[i][5], acc[i][6], acc[i][7]);
                } else {
                    unsigned int* dst = &KVb[(size_t)row * 64 + (m - 1) * 32 + lc * 4];
                    uint4 pk;
                    pk.x = pack2bf(acc[i][0], acc[i][1]);
                    pk.y = pack2bf(acc[i][2], acc[i][3]);
                    pk.z = pack2bf(acc[i][4], acc[i][5]);
                    pk.w = pack2bf(acc[i][6], acc[i][7]);
                    *((uint4*)dst) = pk;
                }
            }
        }
    }
}

// ---------------- QKV' GEMM, variant S: row-per-lane, scalar-W ----------------
// One matrix per block so the single 16 KB W fits scalar K$ (R2 failed with
// 3 W's/block thrashing it). Per k: 1 conflict-free ds_read_b32 (x^T) +
// 16 wave-uniform s_load float4 (K$-hot) + 64 v_fmac with SGPR operand.
// A/B'd against k_qkvT on half the rows this round.
__global__ __launch_bounds__(256) void k_qkvS(const float* __restrict__ x,
                                              const float* __restrict__ Wq,
                                              const float* __restrict__ Wk,
                                              const float* __restrict__ Wvo,
                                              float* __restrict__ Q,
                                              unsigned int* __restrict__ KVb,
                                              int N, int rowBase, int nchunk) {
    __shared__ float xs[4][64 * 64];   // per-wave x^T[k][row]
    int tid = threadIdx.x;
    int wv = tid >> 6;
    int lane = tid & 63;
    int m = blockIdx.x / nchunk;
    int cb = blockIdx.x % nchunk;
    const float* W = (m == 0) ? Wq : ((m == 1) ? Wk : Wvo);

    int base = rowBase + cb * 256 + wv * 64;
    int row = base + lane;
    float* xw = xs[wv];
#pragma unroll
    for (int c4 = 0; c4 < 16; c4++) {
        float4 v = make_float4(0.f, 0.f, 0.f, 0.f);
        if (row < N) v = ((const float4*)x)[(size_t)row * 16 + c4];
        xw[(c4 * 4 + 0) * 64 + lane] = v.x;
        xw[(c4 * 4 + 1) * 64 + lane] = v.y;
        xw[(c4 * 4 + 2) * 64 + lane] = v.z;
        xw[(c4 * 4 + 3) * 64 + lane] = v.w;
    }
    asm volatile("s_waitcnt lgkmcnt(0)" ::: "memory");  // wave-private staging

    float acc[64];
#pragma unroll
    for (int j = 0; j < 64; j++) acc[j] = 0.f;

#pragma unroll 2
    for (int k = 0; k < 64; k++) {
        float xv = xw[k * 64 + lane];
        const float4* Wr = (const float4*)&W[k * 64];
#pragma unroll
        for (int j4 = 0; j4 < 16; j4++) {
            float4 w = Wr[j4];
            acc[j4 * 4 + 0] = fmaf(xv, w.x, acc[j4 * 4 + 0]);
            acc[j4 * 4 + 1] = fmaf(xv, w.y, acc[j4 * 4 + 1]);
            acc[j4 * 4 + 2] = fmaf(xv, w.z, acc[j4 * 4 + 2]);
            acc[j4 * 4 + 3] = fmaf(xv, w.w, acc[j4 * 4 + 3]);
        }
    }

    if (row < N) {
        if (m == 0) {
            float4* dst = (float4*)&Q[(size_t)row * 64];
#pragma unroll
            for (int j4 = 0; j4 < 16; j4++)
                dst[j4] = make_float4(acc[4 * j4], acc[4 * j4 + 1],
                                      acc[4 * j4 + 2], acc[4 * j4 + 3]);
        } else {
            uint4* dst = (uint4*)&KVb[(size_t)row * 64 + (m - 1) * 32];
#pragma unroll
            for (int j2 = 0; j2 < 8; j2++) {
                uint4 pk;
                pk.x = pack2bf(acc[j2 * 8 + 0], acc[j2 * 8 + 1]);
                pk.y = pack2bf(acc[j2 * 8 + 2], acc[j2 * 8 + 3]);
                pk.z = pack2bf(acc[j2 * 8 + 4], acc[j2 * 8 + 5]);
                pk.w = pack2bf(acc[j2 * 8 + 6], acc[j2 * 8 + 7]);
                dst[j2] = pk;
            }
        }
    }
}

// ---------------- attention, bin-local, epilogue-free ----------------
// One block per 32-node group: bb -> super-bin j=bb>>3, sub s=bb&7; its
// contiguous run in ebufB is sofs[j*9+s]..sofs[j*9+s+1]. Grouping and the
// 8-edge bf16 gather pipeline identical to R8.
__global__ __launch_bounds__(256) void k_attn(const float* __restrict__ Q,
                                              const unsigned int* __restrict__ KVb,
                                              const float* __restrict__ x,
                                              const int* __restrict__ sofs,
                                              const unsigned int* __restrict__ ebufB,
                                              float* __restrict__ out, int N) {
    __shared__ unsigned int llist[BCAP];
    __shared__ int ldeg[32], lofs[33], lcur[32];
    int tid = threadIdx.x;
    int wv = tid >> 6;
    int lane = tid & 63;
    int g = lane >> 3;
    int sub = lane & 7;

    int bb = blockIdx.x;
    int sidx = bb + (bb >> 3);            // j*9 + s
    int start0 = sofs[sidx];
    int end0 = sofs[sidx + 1];
    int cnt = min(end0 - start0, BCAP);
    const unsigned int* ebin = ebufB + start0;

    if (tid < 32) ldeg[tid] = 0;
    __syncthreads();

    for (int i = tid; i < cnt; i += 256)
        atomicAdd(&ldeg[(ebin[i] >> 17) & 31], 1);
    __syncthreads();

    if (wv == 0 && lane < 32) {
        int d = ldeg[lane];
        int s = d;
        for (int o = 1; o < 32; o <<= 1) {
            int t = __shfl_up(s, o, 32);
            if ((lane & 31) >= o) s += t;
        }
        lofs[lane + 1] = s;
        lcur[lane] = s - d;
        if (lane == 0) lofs[0] = 0;
    }
    __syncthreads();

    for (int i = tid; i < cnt; i += 256) {
        unsigned int u = ebin[i];
        int n = (u >> 17) & 31;
        int p = atomicAdd(&lcur[n], 1);
        llist[p] = u & 0x1FFFFu;
    }
    __syncthreads();

    int rbase = ((bb >> 3) << 8) + ((bb & 7) << 5);
    for (int n = wv; n < 32; n += 4) {
        int r = rbase + n;
        if (r >= N) break;
        int start = lofs[n];
        int end = lofs[n + 1];
        float4 qa = *((const float4*)&Q[(size_t)r * 64 + sub * 8]);
        float4 qb = *((const float4*)&Q[(size_t)r * 64 + sub * 8 + 4]);
        float q[8] = {qa.x, qa.y, qa.z, qa.w, qb.x, qb.y, qb.z, qb.w};
        float acc[8] = {0.f, 0.f, 0.f, 0.f, 0.f, 0.f, 0.f, 0.f};
        float dpart = 0.f;

        int eA = start + g;
        bool vA = eA < end;
        unsigned int sA = vA ? llist[eA] : 0u;
        uint4 kA = *((const uint4*)&KVb[(size_t)sA * 64 + sub * 4]);
        uint4 uA = *((const uint4*)&KVb[(size_t)sA * 64 + 32 + sub * 4]);
        int eB = start + 8 + g;
        bool vB = eB < end;
        unsigned int sB = vB ? llist[eB] : 0u;
        uint4 kB = *((const uint4*)&KVb[(size_t)sB * 64 + sub * 4]);
        uint4 uB = *((const uint4*)&KVb[(size_t)sB * 64 + 32 + sub * 4]);

        for (int b2 = start; b2 < end; b2 += 8) {
            int eC = b2 + 16 + g;
            bool vC = eC < end;
            unsigned int sC = vC ? llist[eC] : 0u;
            uint4 kC = *((const uint4*)&KVb[(size_t)sC * 64 + sub * 4]);
            uint4 uC = *((const uint4*)&KVb[(size_t)sC * 64 + 32 + sub * 4]);

            float2 k01 = unpack2bf(kA.x), k23 = unpack2bf(kA.y);
            float2 k45 = unpack2bf(kA.z), k67 = unpack2bf(kA.w);
            float dot = q[0] * k01.x + q[1] * k01.y + q[2] * k23.x + q[3] * k23.y
                      + q[4] * k45.x + q[5] * k45.y + q[6] * k67.x + q[7] * k67.y;
            dot += __shfl_xor(dot, 1);
            dot += __shfl_xor(dot, 2);
            dot += __shfl_xor(dot, 4);
            float w = vA ? __expf(dot * SCALE) : 0.f;

            float2 v01 = unpack2bf(uA.x), v23 = unpack2bf(uA.y);
            float2 v45 = unpack2bf(uA.z), v67 = unpack2bf(uA.w);
            acc[0] = fmaf(w, v01.x, acc[0]);
            acc[1] = fmaf(w, v01.y, acc[1]);
            acc[2] = fmaf(w, v23.x, acc[2]);
            acc[3] = fmaf(w, v23.y, acc[3]);
            acc[4] = fmaf(w, v45.x, acc[4]);
            acc[5] = fmaf(w, v45.y, acc[5]);
            acc[6] = fmaf(w, v67.x, acc[6]);
            acc[7] = fmaf(w, v67.y, acc[7]);
            dpart += w;

            kA = kB; uA = uB; vA = vB;
            kB = kC; uB = uC; vB = vC;
        }

        dpart += __shfl_xor(dpart, 8); dpart += __shfl_xor(dpart, 16); dpart += __shfl_xor(dpart, 32);
#pragma unroll
        for (int jj = 0; jj < 8; jj++) {
            acc[jj] += __shfl_xor(acc[jj], 8);
            acc[jj] += __shfl_xor(acc[jj], 16);
            acc[jj] += __shfl_xor(acc[jj], 32);
        }

        float inv = (dpart > 0.f) ? (1.0f / dpart) : 0.f;

        if (g == 0) {
            float4 xa = *((const float4*)&x[(size_t)r * 64 + sub * 8]);
            float4 xb = *((const float4*)&x[(size_t)r * 64 + sub * 8 + 4]);
            float4 oa = make_float4(fmaf(acc[0], inv, xa.x), fmaf(acc[1], inv, xa.y),
                                    fmaf(acc[2], inv, xa.z), fmaf(acc[3], inv, xa.w));
            float4 ob = make_float4(fmaf(acc[4], inv, xb.x), fmaf(acc[5], inv, xb.y),
                                    fmaf(acc[6], inv, xb.z), fmaf(acc[7], inv, xb.w));
            *((float4*)&out[(size_t)r * 64 + sub * 8]) = oa;
            *((float4*)&out[(size_t)r * 64 + sub * 8 + 4]) = ob;
        }
    }
}

// ---------------- launch ----------------

extern "C" void kernel_launch(void* const* d_in, const int* in_sizes, int n_in,
                              void* d_out, int out_size, void* d_ws, size_t ws_size,
                              hipStream_t stream) {
    const float* x  = (const float*)d_in[0];
    const int* edge = (const int*)d_in[1];
    const float* Wq = (const float*)d_in[2];
    const float* Wk = (const float*)d_in[3];
    const float* Wv = (const float*)d_in[4];
    const float* Wo = (const float*)d_in[5];
    float* out = (float*)d_out;

    int N = in_sizes[0] / DIM;
    int E = in_sizes[1] / 2;
    int NSUP = (N + 255) >> 8;

    char* p = (char*)d_ws;
    auto cv = [&](size_t bytes) {
        char* r = p;
        p += ((bytes + 255) / 256) * 256;
        return r;
    };
    float*        Q      = (float*)cv((size_t)N * 64 * 4);
    unsigned int* KVb    = (unsigned int*)cv((size_t)N * 64 * 4);
    float*        Wvo    = (float*)cv(64 * 64 * 4);
    int*          binCur = (int*)cv((size_t)NSUP * 4);
    int*          sofs   = (int*)cv((size_t)NSUP * 9 * 4 + 4);
    unsigned int* ebufA  = (unsigned int*)cv((size_t)NSUP * SCAP * 4);
    unsigned int* ebufB  = (unsigned int*)cv((size_t)NSUP * SCAP * 4);
    (void)ws_size; (void)n_in; (void)out_size;

    const int* send = edge;
    const int* recv = edge + E;

    hipMemsetAsync(binCur, 0, (size_t)NSUP * 4, stream);
    k_bin1<<<(E + CHUNK1 - 1) / CHUNK1, 512, 0, stream>>>(send, recv, binCur, ebufA, E, NSUP);
    k_bin2<<<NSUP, 256, 0, stream>>>(binCur, ebufA, ebufB, sofs);
    k_wmul<<<64, 64, 0, stream>>>(Wv, Wo, Wvo);

    // A/B split: rows [0,rowsT) via tile variant, [rowsT,N) via scalar-W variant
    int rowsT = 196 * 256;
    if (rowsT > N) rowsT = N;
    int nchT = (rowsT + 255) / 256;
    int nchS = (N - rowsT + 255) / 256;
    if (nchT > 0)
        k_qkvT<<<3 * nchT, 256, 0, stream>>>(x, Wq, Wk, Wvo, Q, KVb, N, 0, nchT);
    if (nchS > 0)
        k_qkvS<<<3 * nchS, 256, 0, stream>>>(x, Wq, Wk, Wvo, Q, KVb, N, rowsT, nchS);

    k_attn<<<NSUP * 8, 256, 0, stream>>>(Q, KVb, x, sofs, ebufB, out, N);
}